// Round 16
// baseline (1529.308 us; speedup 1.0000x reference)
//
#include <hip/hip_runtime.h>
#include <hip/hip_fp16.h>
#include <cstdint>
#include <cmath>

// GCN, 4 layers. Structure: A(hW) = (Ah)W with norm folded into features:
//   g = dis (.) h  stored FP16,
//   A_norm h [d] = dis[d] * ( sum_e w_e * g[src_e] + g[d] )
// CSR via two-level LDS counting sort (R12).
//
// R16: layers 1-3 rebuilt EDGE-PARALLEL. R13-R15 evidence: node-parallel
// aggregation is latency-bound on per-node serial chains + Poisson(12) tail
// imbalance (micro-ILP tweaks regressed twice). New: block = 64 dst nodes,
// its CSR edge range split across 32 lane-groups BY EDGE (24+-1 edges/group,
// perfectly balanced), coalesced pairs reads, unroll-4 gathers, ds_add_f32
// LDS accumulation into fp32 rows[64][65] (dst-local6 rides free in pairs.x
// bits 17+, already written by the counting sort). Phase 2: node=lane,
// 16 cols/wave fp32 GEMM, self-term+dis+ELU fused. Layer 4 stays R13-form.

#define NPB_SHIFT 9
#define NPB 512              // nodes per bucket (CSR build)
#define CHUNK 4096           // edges per block in count/scatter passes
#define SRCMASK 0x1FFFF      // low 17 bits of pairs.x = src node

// ---- fdot2: 2x f16 MAC with fp32 accumulator (guarded builtin) [layer4]
__device__ __forceinline__ float fdot2f(__half2 a, __half2 b, float c) {
#if defined(__has_builtin)
#if __has_builtin(__builtin_amdgcn_fdot2)
    typedef _Float16 h2v __attribute__((ext_vector_type(2)));
    return __builtin_amdgcn_fdot2(__builtin_bit_cast(h2v, a),
                                  __builtin_bit_cast(h2v, b), c, false);
#else
    float2 fa = __half22float2(a), fb = __half22float2(b);
    return fmaf(fa.x, fb.x, fmaf(fa.y, fb.y, c));
#endif
#else
    float2 fa = __half22float2(a), fb = __half22float2(b);
    return fmaf(fa.x, fb.x, fmaf(fa.y, fb.y, c));
#endif
}

// ---- wave-local LDS fence (layer4 phase handoff)
__device__ __forceinline__ void wave_lds_fence() {
    asm volatile("s_waitcnt lgkmcnt(0)" ::: "memory");
    __builtin_amdgcn_wave_barrier();
    __builtin_amdgcn_sched_barrier(0);
}

// ------------------------------------------- CSR build: two-level counting sort

__global__ __launch_bounds__(256) void bucket_count_kernel(const int* __restrict__ dst,
                                                           int* __restrict__ bucket_cnt,
                                                           int* __restrict__ blockbase,
                                                           int nbuck, int E) {
    __shared__ int hist[256];
    int tid = threadIdx.x;
    hist[tid] = 0;
    __syncthreads();
    int base = blockIdx.x * CHUNK;
    #pragma unroll
    for (int u = 0; u < CHUNK / 256; ++u) {
        int e = base + u * 256 + tid;
        if (e < E) atomicAdd(&hist[dst[e] >> NPB_SHIFT], 1);
    }
    __syncthreads();
    if (tid < nbuck)
        blockbase[blockIdx.x * nbuck + tid] = atomicAdd(&bucket_cnt[tid], hist[tid]);
}

__global__ __launch_bounds__(64) void bucket_scan_kernel(const int* __restrict__ bucket_cnt,
                                                         int* __restrict__ bucket_base,
                                                         int nbuck, int E) {
    int lane = threadIdx.x;
    int run = 0;
    for (int b0 = 0; b0 < nbuck; b0 += 64) {
        int i = b0 + lane;
        int v = (i < nbuck) ? bucket_cnt[i] : 0;
        int x = v;
        #pragma unroll
        for (int off = 1; off < 64; off <<= 1) {
            int t = __shfl_up(x, off);
            if (lane >= off) x += t;
        }
        if (i < nbuck) bucket_base[i] = run + x - v;
        run += __shfl(x, 63);
    }
    if (lane == 0) bucket_base[nbuck] = E;
}

__global__ __launch_bounds__(256) void bucket_scatter_kernel(const int* __restrict__ src,
                                                             const int* __restrict__ dst,
                                                             const float* __restrict__ w,
                                                             const int* __restrict__ bucket_base,
                                                             const int* __restrict__ blockbase,
                                                             int2* __restrict__ temp,
                                                             int nbuck, int E) {
    __shared__ int cursor[256];
    int tid = threadIdx.x;
    if (tid < nbuck)
        cursor[tid] = bucket_base[tid] + blockbase[blockIdx.x * nbuck + tid];
    __syncthreads();
    int base = blockIdx.x * CHUNK;
    #pragma unroll
    for (int u = 0; u < CHUNK / 256; ++u) {
        int e = base + u * 256 + tid;
        if (e < E) {
            int d = dst[e];
            int pos = atomicAdd(&cursor[d >> NPB_SHIFT], 1);
            temp[pos] = make_int2(src[e] | ((d & (NPB - 1)) << 17),
                                  __float_as_int(w[e]));
        }
    }
}

// pairs keeps the full (src | local9<<17) — local9 & 63 = dst's id within any
// 64-aligned layer block (buckets are 512-aligned). Consumers mask with SRCMASK.
__global__ __launch_bounds__(256) void bucket_csr_kernel(const int2* __restrict__ temp,
                                                         const int* __restrict__ bucket_base,
                                                         int* __restrict__ offsets,
                                                         int2* __restrict__ pairs,
                                                         int n, int E) {
    __shared__ int cnt[NPB];
    __shared__ int wtot[4];
    int tid = threadIdx.x;
    int bk = blockIdx.x;
    int base = bucket_base[bk], end = bucket_base[bk + 1];
    cnt[tid] = 0; cnt[tid + 256] = 0;
    __syncthreads();
    for (int j = base + tid; j < end; j += 256)
        atomicAdd(&cnt[temp[j].x >> 17], 1);
    __syncthreads();
    int a0 = cnt[2 * tid], a1 = cnt[2 * tid + 1];
    int s = a0 + a1;
    int lane = tid & 63, wid = tid >> 6;
    int x = s;
    #pragma unroll
    for (int off = 1; off < 64; off <<= 1) {
        int t2 = __shfl_up(x, off);
        if (lane >= off) x += t2;
    }
    if (lane == 63) wtot[wid] = x;
    __syncthreads();
    int wbase = 0;
    #pragma unroll
    for (int wv = 0; wv < 4; ++wv) if (wv < wid) wbase += wtot[wv];
    int e0 = wbase + x - s;
    int abs0 = base + e0, abs1 = base + e0 + a0;
    int node0 = bk * NPB + 2 * tid;
    if (node0 < n)     offsets[node0]     = abs0;
    if (node0 + 1 < n) offsets[node0 + 1] = abs1;
    __syncthreads();
    cnt[2 * tid] = abs0; cnt[2 * tid + 1] = abs1;
    __syncthreads();
    for (int j = base + tid; j < end; j += 256) {
        int2 t2 = temp[j];
        int pos = atomicAdd(&cnt[t2.x >> 17], 1);
        pairs[pos] = t2;                       // keep dst-local bits
    }
    if (bk == 0 && tid == 0) offsets[n] = E;
}

// fused: deg row-sum -> dis -> g0 = fp16(dis (.) x). 16 lanes per node.
__global__ __launch_bounds__(256) void rowsum_scale_kernel(const int* __restrict__ offsets,
                                                           const int2* __restrict__ pairs,
                                                           const float* __restrict__ x,
                                                           float* __restrict__ dis,
                                                           __half* __restrict__ g, int n) {
    int node = blockIdx.x * 16 + (threadIdx.x >> 4);
    int q = threadIdx.x & 15;
    if (node >= n) return;
    int j0 = offsets[node], end = offsets[node + 1];
    float s = 0.f;
    for (int j = j0 + q; j < end; j += 16) s += __int_as_float(pairs[j].y);
    #pragma unroll
    for (int off = 8; off; off >>= 1) s += __shfl_xor(s, off);
    float dn = rsqrtf(1.0f + s);
    if (q == 0) dis[node] = dn;
    float4 v = reinterpret_cast<const float4*>(x)[(size_t)node * 16 + q];
    __half2 pk[2];
    pk[0] = __float22half2_rn(make_float2(dn * v.x, dn * v.y));
    pk[1] = __float22half2_rn(make_float2(dn * v.z, dn * v.w));
    reinterpret_cast<float2*>(g + (size_t)node * 64)[q] = *reinterpret_cast<float2*>(pk);
}

// -------------------------------- layers 1-3: EDGE-PARALLEL aggregate -> GEMM64
// Block = 64 dst nodes. Phase 1: 32 lane-groups stride the block's CSR edge
// range (balanced by edge count); group g, lane q gathers the src row's half8
// #q and ds_add_f32-accumulates into rows[dl][q*8..]. Phase 2: node = lane,
// cols [16*wave, +16); row = dn*(acc + self); fp32 GEMM from LDS; ELU+dn; fp16.
__global__ __launch_bounds__(256) void layer_fused_kernel(const __half* __restrict__ gin,
                                                          const float* __restrict__ dis,
                                                          const int* __restrict__ offsets,
                                                          const int2* __restrict__ pairs,
                                                          const float* __restrict__ W,
                                                          const float* __restrict__ b,
                                                          __half* __restrict__ gout, int n) {
    __shared__ float rows[64][65];   // fp32 accumulators, stride 65 (conflict-free)
    __shared__ float WT[64][64];     // WT[c][k] = W[k][c] (wave-uniform reads)
    __shared__ float bias_s[64];

    int tid = threadIdx.x;
    for (int idx = tid; idx < 64 * 64; idx += 256) {
        int k = idx >> 6, c = idx & 63;
        WT[c][k] = W[idx];
    }
    if (tid < 64) bias_s[tid] = b[tid];
    for (int idx = tid; idx < 64 * 65; idx += 256)
        (&rows[0][0])[idx] = 0.f;
    __syncthreads();

    int base = blockIdx.x * 64;
    int nend = (base + 64 < n) ? base + 64 : n;
    int estart = offsets[base];
    int eend   = offsets[nend];

    int g = tid >> 3;                 // 32 edge-groups
    int q = tid & 7;                  // half8 slot
    const float4* gt = reinterpret_cast<const float4*>(gin);

    int e = estart + g;
    // unroll-4: 4 independent gathers in flight (strides of 32 edges)
    for (; e + 96 < eend; e += 128) {
        int2 p0 = pairs[e], p1 = pairs[e + 32], p2 = pairs[e + 64], p3 = pairs[e + 96];
        float4 r0 = gt[(size_t)(p0.x & SRCMASK) * 8 + q];
        float4 r1 = gt[(size_t)(p1.x & SRCMASK) * 8 + q];
        float4 r2 = gt[(size_t)(p2.x & SRCMASK) * 8 + q];
        float4 r3 = gt[(size_t)(p3.x & SRCMASK) * 8 + q];
        {
            float w = __int_as_float(p0.y);
            float* rp = &rows[(p0.x >> 17) & 63][q * 8];
            const __half2* h = reinterpret_cast<const __half2*>(&r0);
            #pragma unroll
            for (int k = 0; k < 4; ++k) {
                float2 f = __half22float2(h[k]);
                atomicAdd(rp + 2 * k,     w * f.x);
                atomicAdd(rp + 2 * k + 1, w * f.y);
            }
        }
        {
            float w = __int_as_float(p1.y);
            float* rp = &rows[(p1.x >> 17) & 63][q * 8];
            const __half2* h = reinterpret_cast<const __half2*>(&r1);
            #pragma unroll
            for (int k = 0; k < 4; ++k) {
                float2 f = __half22float2(h[k]);
                atomicAdd(rp + 2 * k,     w * f.x);
                atomicAdd(rp + 2 * k + 1, w * f.y);
            }
        }
        {
            float w = __int_as_float(p2.y);
            float* rp = &rows[(p2.x >> 17) & 63][q * 8];
            const __half2* h = reinterpret_cast<const __half2*>(&r2);
            #pragma unroll
            for (int k = 0; k < 4; ++k) {
                float2 f = __half22float2(h[k]);
                atomicAdd(rp + 2 * k,     w * f.x);
                atomicAdd(rp + 2 * k + 1, w * f.y);
            }
        }
        {
            float w = __int_as_float(p3.y);
            float* rp = &rows[(p3.x >> 17) & 63][q * 8];
            const __half2* h = reinterpret_cast<const __half2*>(&r3);
            #pragma unroll
            for (int k = 0; k < 4; ++k) {
                float2 f = __half22float2(h[k]);
                atomicAdd(rp + 2 * k,     w * f.x);
                atomicAdd(rp + 2 * k + 1, w * f.y);
            }
        }
    }
    for (; e < eend; e += 32) {
        int2 p = pairs[e];
        float4 rv = gt[(size_t)(p.x & SRCMASK) * 8 + q];
        float w = __int_as_float(p.y);
        float* rp = &rows[(p.x >> 17) & 63][q * 8];
        const __half2* h = reinterpret_cast<const __half2*>(&rv);
        #pragma unroll
        for (int k = 0; k < 4; ++k) {
            float2 f = __half22float2(h[k]);
            atomicAdd(rp + 2 * k,     w * f.x);
            atomicAdd(rp + 2 * k + 1, w * f.y);
        }
    }
    __syncthreads();

    // ---- phase 2: GEMM64 + bias + ELU + dn, node = lane, 16 cols per wave
    int lane = tid & 63, wave = tid >> 6;
    int gnode = base + lane;
    if (gnode < n) {
        float dn = dis[gnode];
        float row[64];
        const float4* selfp = gt + (size_t)gnode * 8;
        #pragma unroll
        for (int j = 0; j < 8; ++j) {
            float4 rv = selfp[j];
            const __half2* h = reinterpret_cast<const __half2*>(&rv);
            #pragma unroll
            for (int k = 0; k < 4; ++k) {
                float2 f = __half22float2(h[k]);
                row[j * 8 + 2 * k]     = dn * (rows[lane][j * 8 + 2 * k]     + f.x);
                row[j * 8 + 2 * k + 1] = dn * (rows[lane][j * 8 + 2 * k + 1] + f.y);
            }
        }
        int c0 = wave * 16;
        float r[16];
        #pragma unroll
        for (int cc = 0; cc < 16; ++cc) {
            const float* wt = &WT[c0 + cc][0];
            float a0 = 0.f, a1 = 0.f, a2 = 0.f, a3 = 0.f;
            #pragma unroll
            for (int k = 0; k < 16; ++k) {
                a0 = fmaf(row[4 * k],     wt[4 * k],     a0);
                a1 = fmaf(row[4 * k + 1], wt[4 * k + 1], a1);
                a2 = fmaf(row[4 * k + 2], wt[4 * k + 2], a2);
                a3 = fmaf(row[4 * k + 3], wt[4 * k + 3], a3);
            }
            float v = (a0 + a1) + (a2 + a3) + bias_s[c0 + cc];
            v = (v > 0.f) ? v : expm1f(v);          // ELU
            r[cc] = dn * v;                          // pre-scale for next layer
        }
        __half2 pk[8];
        #pragma unroll
        for (int i = 0; i < 8; ++i)
            pk[i] = __float22half2_rn(make_float2(r[2 * i], r[2 * i + 1]));
        float4* outp = reinterpret_cast<float4*>(gout + (size_t)gnode * 64 + c0);
        outp[0] = reinterpret_cast<float4*>(pk)[0];
        outp[1] = reinterpret_cast<float4*>(pk)[1];
    }
}

// ---------------------------------------------------------------- layer-4 path
// (R13-proven node-parallel form; pairs.x now masked for src)
__device__ __forceinline__ void accum8(float* acc, float4 rv, float w) {
    const __half2* h = reinterpret_cast<const __half2*>(&rv);
    #pragma unroll
    for (int k = 0; k < 4; ++k) {
        float2 f = __half22float2(h[k]);
        acc[2 * k]     = fmaf(w, f.x, acc[2 * k]);
        acc[2 * k + 1] = fmaf(w, f.y, acc[2 * k + 1]);
    }
}

__device__ __forceinline__ void agg_tail(const float4* __restrict__ gt,
                                         const int2* __restrict__ pairs,
                                         int j, int end, int q,
                                         float* __restrict__ acc) {
    for (; j + 4 <= end; j += 4) {
        int2 p0 = pairs[j], p1 = pairs[j + 1], p2 = pairs[j + 2], p3 = pairs[j + 3];
        float4 r0 = gt[(size_t)(p0.x & SRCMASK) * 8 + q];
        float4 r1 = gt[(size_t)(p1.x & SRCMASK) * 8 + q];
        float4 r2 = gt[(size_t)(p2.x & SRCMASK) * 8 + q];
        float4 r3 = gt[(size_t)(p3.x & SRCMASK) * 8 + q];
        accum8(acc, r0, __int_as_float(p0.y));
        accum8(acc, r1, __int_as_float(p1.y));
        accum8(acc, r2, __int_as_float(p2.y));
        accum8(acc, r3, __int_as_float(p3.y));
    }
    for (; j < end; ++j) {
        int2 p = pairs[j];
        float4 r = gt[(size_t)(p.x & SRCMASK) * 8 + q];
        accum8(acc, r, __int_as_float(p.y));
    }
}

__device__ __forceinline__ void phase1_agg(const __half* __restrict__ gin,
                                           const float* __restrict__ dis,
                                           const int* __restrict__ offsets,
                                           const int2* __restrict__ pairs,
                                           __half2 (*rows)[33], int n, int tid,
                                           int blockbase_node) {
    int ln = tid >> 3;
    int q  = tid & 7;
    int gnode = blockbase_node + ln;
    if (gnode < n) {
        const float4* gt = reinterpret_cast<const float4*>(gin);
        float acc[8] = {0.f, 0.f, 0.f, 0.f, 0.f, 0.f, 0.f, 0.f};
        agg_tail(gt, pairs, offsets[gnode], offsets[gnode + 1], q, acc);
        float4 rs = gt[(size_t)gnode * 8 + q];   // self term, weight 1
        accum8(acc, rs, 1.0f);
        float dn = dis[gnode];
        #pragma unroll
        for (int k2 = 0; k2 < 4; ++k2)
            rows[ln][q * 4 + k2] =
                __float22half2_rn(make_float2(dn * acc[2 * k2], dn * acc[2 * k2 + 1]));
    }
}

__global__ __launch_bounds__(256) void layer4_fused_kernel(const __half* __restrict__ gin,
                                                           const float* __restrict__ dis,
                                                           const int* __restrict__ offsets,
                                                           const int2* __restrict__ pairs,
                                                           const float* __restrict__ W,
                                                           const float* __restrict__ b,
                                                           float* __restrict__ out, int n) {
    __shared__ __half2 rows[32][33];
    __shared__ __half2 WT[40][33];
    __shared__ float bias_s[40];
    for (int idx = threadIdx.x; idx < 40 * 32; idx += 256) {
        int c = idx % 40, k2 = idx / 40;
        WT[c][k2] = __float22half2_rn(make_float2(W[(2 * k2) * 40 + c],
                                                  W[(2 * k2 + 1) * 40 + c]));
    }
    if (threadIdx.x < 40) bias_s[threadIdx.x] = b[threadIdx.x];
    __syncthreads();

    int tid = threadIdx.x;
    phase1_agg(gin, dis, offsets, pairs, rows, n, tid, blockIdx.x * 32);
    wave_lds_fence();

    int lane  = tid & 63, wave = tid >> 6;
    int node2 = wave * 8 + (lane & 7);
    int slice = lane >> 3;                 // classes [5*slice, 5*slice+5)
    int gnode2 = blockIdx.x * 32 + node2;

    float r[5];
    float mp = -__builtin_inff();
    if (gnode2 < n) {
        __half2 h2[32];
        #pragma unroll
        for (int i = 0; i < 32; ++i) h2[i] = rows[node2][i];
        int c0 = slice * 5;
        #pragma unroll
        for (int cc = 0; cc < 5; ++cc) {
            const __half2* wt = &WT[c0 + cc][0];
            float a0 = 0.f, a1 = 0.f, a2 = 0.f, a3 = 0.f;
            #pragma unroll
            for (int i = 0; i < 8; ++i) {
                a0 = fdot2f(h2[4 * i],     wt[4 * i],     a0);
                a1 = fdot2f(h2[4 * i + 1], wt[4 * i + 1], a1);
                a2 = fdot2f(h2[4 * i + 2], wt[4 * i + 2], a2);
                a3 = fdot2f(h2[4 * i + 3], wt[4 * i + 3], a3);
            }
            r[cc] = (a0 + a1) + (a2 + a3) + bias_s[c0 + cc];
            mp = fmaxf(mp, r[cc]);
        }
    }
    mp = fmaxf(mp, __shfl_xor(mp, 8));
    mp = fmaxf(mp, __shfl_xor(mp, 16));
    mp = fmaxf(mp, __shfl_xor(mp, 32));
    float sp = 0.f;
    if (gnode2 < n) {
        #pragma unroll
        for (int cc = 0; cc < 5; ++cc) sp += expf(r[cc] - mp);
    }
    sp += __shfl_xor(sp, 8);
    sp += __shfl_xor(sp, 16);
    sp += __shfl_xor(sp, 32);
    if (gnode2 < n) {
        float ls = logf(sp) + mp;
        float* outp = out + (size_t)gnode2 * 40 + slice * 5;
        #pragma unroll
        for (int cc = 0; cc < 5; ++cc) outp[cc] = r[cc] - ls;
    }
}

// ---------------------------------------------------------------- launch

static inline size_t align_up(size_t x, size_t a) { return (x + a - 1) & ~(a - 1); }

extern "C" void kernel_launch(void* const* d_in, const int* in_sizes, int n_in,
                              void* d_out, int out_size, void* d_ws, size_t ws_size,
                              hipStream_t stream) {
    const float* x  = (const float*)d_in[0];
    const int*   ei = (const int*)d_in[1];     // [2][E] flat: src then dst
    const float* ea = (const float*)d_in[2];
    const float* W1 = (const float*)d_in[3];
    const float* b1 = (const float*)d_in[4];
    const float* W2 = (const float*)d_in[5];
    const float* b2 = (const float*)d_in[6];
    const float* W3 = (const float*)d_in[7];
    const float* b3 = (const float*)d_in[8];
    const float* W4 = (const float*)d_in[9];
    const float* b4 = (const float*)d_in[10];

    const int N = in_sizes[0] / 64;
    const int E = in_sizes[1] / 2;

    const int* src = ei;
    const int* dst = ei + E;

    const int nbuck   = (N + NPB - 1) >> NPB_SHIFT;      // 196 for N=100K (<=256)
    const int nblk_ac = (E + CHUNK - 1) / CHUNK;         // 293

    // workspace carve-up
    char* p = (char*)d_ws;
    int*    offsets     = (int*)p;  p += align_up(((size_t)N + 1) * 4, 256);
    int*    bucket_cnt  = (int*)p;  p += align_up(((size_t)nbuck + 1) * 4, 256);
    int*    bucket_base = (int*)p;  p += align_up(((size_t)nbuck + 1) * 4, 256);
    int*    blockbase   = (int*)p;  p += align_up((size_t)nblk_ac * nbuck * 4, 256);
    float*  dis         = (float*)p; p += align_up((size_t)N * 4, 256);
    int2*   pairs       = (int2*)p;  p += align_up(((size_t)E + 8) * 8, 256);
    int2*   temp        = (int2*)p;  p += align_up(((size_t)E + 8) * 8, 256);
    __half* gA          = (__half*)p; p += align_up((size_t)N * 64 * 2, 256);
    __half* gB          = (__half*)p; p += align_up((size_t)N * 64 * 2, 256);
    (void)ws_size;

    const int nb_g16 = (N + 15) / 16;
    const int nb_f   = (N + 63) / 64;           // layers 1-3: 64 nodes/block
    const int nb_f4  = (N + 31) / 32;           // layer 4: 32 nodes/block

    // --- CSR build (two-level counting sort, LDS-privatized) ---
    hipMemsetAsync(bucket_cnt, 0, (size_t)(nbuck + 1) * 4, stream);
    bucket_count_kernel<<<nblk_ac, 256, 0, stream>>>(dst, bucket_cnt, blockbase, nbuck, E);
    bucket_scan_kernel<<<1, 64, 0, stream>>>(bucket_cnt, bucket_base, nbuck, E);
    bucket_scatter_kernel<<<nblk_ac, 256, 0, stream>>>(src, dst, ea, bucket_base,
                                                       blockbase, temp, nbuck, E);
    bucket_csr_kernel<<<nbuck, 256, 0, stream>>>(temp, bucket_base, offsets, pairs, N, E);
    rowsum_scale_kernel<<<nb_g16, 256, 0, stream>>>(offsets, pairs, x, dis, gA, N);

    // --- layers 1..3: edge-parallel aggregate -> GEMM64+ELU -> fp16 ---
    layer_fused_kernel<<<nb_f, 256, 0, stream>>>(gA, dis, offsets, pairs, W1, b1, gB, N);
    layer_fused_kernel<<<nb_f, 256, 0, stream>>>(gB, dis, offsets, pairs, W2, b2, gA, N);
    layer_fused_kernel<<<nb_f, 256, 0, stream>>>(gA, dis, offsets, pairs, W3, b3, gB, N);

    // --- layer 4 fused: aggregate -> GEMM40 -> log_softmax -> d_out ---
    layer4_fused_kernel<<<nb_f4, 256, 0, stream>>>(gB, dis, offsets, pairs, W4, b4,
                                                   (float*)d_out, N);
}

// Round 17
// 239.964 us; speedup vs baseline: 6.3731x; 6.3731x over previous
//
#include <hip/hip_runtime.h>
#include <hip/hip_fp16.h>
#include <cstdint>
#include <cmath>

// GCN, 4 layers. Structure: A(hW) = (Ah)W with norm folded into features:
//   g = dis (.) h  stored FP16,
//   A_norm h [d] = dis[d] * ( sum_e w_e * g[src_e] + g[d] )
// CSR via two-level LDS counting sort (R12). Layers wave-autonomous (R13).
//
// R17: full revert to R13 (208us; R14/R15/R16 all regressed -- lessons:
// fp16-pack/lane-flip = null+conflicts; dual-node = occupancy loss;
// edge-parallel LDS float atomics = 7x catastrophic). ONE isolated change:
// the gather loop issues 8 pairs loads back-to-back, then 8 row-gathers,
// then accumulates (R13 was 4-wide interleaved). In-order issue means the
// 4-wide loop pays lat(pairs)+lat(gather) per 4 edges; 8-deep batch halves
// the serialized latency chain per node. fp32 accum + R13 lane maps kept.

#define NPB_SHIFT 9
#define NPB 512              // nodes per bucket
#define CHUNK 4096           // edges per block in count/scatter passes

// ---- fdot2: 2x f16 MAC with fp32 accumulator (guarded builtin)
__device__ __forceinline__ float fdot2f(__half2 a, __half2 b, float c) {
#if defined(__has_builtin)
#if __has_builtin(__builtin_amdgcn_fdot2)
    typedef _Float16 h2v __attribute__((ext_vector_type(2)));
    return __builtin_amdgcn_fdot2(__builtin_bit_cast(h2v, a),
                                  __builtin_bit_cast(h2v, b), c, false);
#else
    float2 fa = __half22float2(a), fb = __half22float2(b);
    return fmaf(fa.x, fb.x, fmaf(fa.y, fb.y, c));
#endif
#else
    float2 fa = __half22float2(a), fb = __half22float2(b);
    return fmaf(fa.x, fb.x, fmaf(fa.y, fb.y, c));
#endif
}

// ---- wave-local LDS fence: all this wave's ds_writes visible to its ds_reads
__device__ __forceinline__ void wave_lds_fence() {
    asm volatile("s_waitcnt lgkmcnt(0)" ::: "memory");
    __builtin_amdgcn_wave_barrier();
    __builtin_amdgcn_sched_barrier(0);
}

// ------------------------------------------- CSR build: two-level counting sort

__global__ __launch_bounds__(256) void bucket_count_kernel(const int* __restrict__ dst,
                                                           int* __restrict__ bucket_cnt,
                                                           int* __restrict__ blockbase,
                                                           int nbuck, int E) {
    __shared__ int hist[256];
    int tid = threadIdx.x;
    hist[tid] = 0;
    __syncthreads();
    int base = blockIdx.x * CHUNK;
    #pragma unroll
    for (int u = 0; u < CHUNK / 256; ++u) {
        int e = base + u * 256 + tid;
        if (e < E) atomicAdd(&hist[dst[e] >> NPB_SHIFT], 1);
    }
    __syncthreads();
    if (tid < nbuck)
        blockbase[blockIdx.x * nbuck + tid] = atomicAdd(&bucket_cnt[tid], hist[tid]);
}

__global__ __launch_bounds__(64) void bucket_scan_kernel(const int* __restrict__ bucket_cnt,
                                                         int* __restrict__ bucket_base,
                                                         int nbuck, int E) {
    int lane = threadIdx.x;
    int run = 0;
    for (int b0 = 0; b0 < nbuck; b0 += 64) {
        int i = b0 + lane;
        int v = (i < nbuck) ? bucket_cnt[i] : 0;
        int x = v;
        #pragma unroll
        for (int off = 1; off < 64; off <<= 1) {
            int t = __shfl_up(x, off);
            if (lane >= off) x += t;
        }
        if (i < nbuck) bucket_base[i] = run + x - v;
        run += __shfl(x, 63);
    }
    if (lane == 0) bucket_base[nbuck] = E;
}

__global__ __launch_bounds__(256) void bucket_scatter_kernel(const int* __restrict__ src,
                                                             const int* __restrict__ dst,
                                                             const float* __restrict__ w,
                                                             const int* __restrict__ bucket_base,
                                                             const int* __restrict__ blockbase,
                                                             int2* __restrict__ temp,
                                                             int nbuck, int E) {
    __shared__ int cursor[256];
    int tid = threadIdx.x;
    if (tid < nbuck)
        cursor[tid] = bucket_base[tid] + blockbase[blockIdx.x * nbuck + tid];
    __syncthreads();
    int base = blockIdx.x * CHUNK;
    #pragma unroll
    for (int u = 0; u < CHUNK / 256; ++u) {
        int e = base + u * 256 + tid;
        if (e < E) {
            int d = dst[e];
            int pos = atomicAdd(&cursor[d >> NPB_SHIFT], 1);
            temp[pos] = make_int2(src[e] | ((d & (NPB - 1)) << 17),
                                  __float_as_int(w[e]));
        }
    }
}

__global__ __launch_bounds__(256) void bucket_csr_kernel(const int2* __restrict__ temp,
                                                         const int* __restrict__ bucket_base,
                                                         int* __restrict__ offsets,
                                                         int2* __restrict__ pairs,
                                                         int n, int E) {
    __shared__ int cnt[NPB];
    __shared__ int wtot[4];
    int tid = threadIdx.x;
    int bk = blockIdx.x;
    int base = bucket_base[bk], end = bucket_base[bk + 1];
    cnt[tid] = 0; cnt[tid + 256] = 0;
    __syncthreads();
    for (int j = base + tid; j < end; j += 256)
        atomicAdd(&cnt[temp[j].x >> 17], 1);
    __syncthreads();
    int a0 = cnt[2 * tid], a1 = cnt[2 * tid + 1];
    int s = a0 + a1;
    int lane = tid & 63, wid = tid >> 6;
    int x = s;
    #pragma unroll
    for (int off = 1; off < 64; off <<= 1) {
        int t2 = __shfl_up(x, off);
        if (lane >= off) x += t2;
    }
    if (lane == 63) wtot[wid] = x;
    __syncthreads();
    int wbase = 0;
    #pragma unroll
    for (int wv = 0; wv < 4; ++wv) if (wv < wid) wbase += wtot[wv];
    int e0 = wbase + x - s;
    int abs0 = base + e0, abs1 = base + e0 + a0;
    int node0 = bk * NPB + 2 * tid;
    if (node0 < n)     offsets[node0]     = abs0;
    if (node0 + 1 < n) offsets[node0 + 1] = abs1;
    __syncthreads();
    cnt[2 * tid] = abs0; cnt[2 * tid + 1] = abs1;
    __syncthreads();
    for (int j = base + tid; j < end; j += 256) {
        int2 t2 = temp[j];
        int pos = atomicAdd(&cnt[t2.x >> 17], 1);
        pairs[pos] = make_int2(t2.x & 0x1FFFF, t2.y);
    }
    if (bk == 0 && tid == 0) offsets[n] = E;
}

// fused: deg row-sum -> dis -> g0 = fp16(dis (.) x). 16 lanes per node.
__global__ __launch_bounds__(256) void rowsum_scale_kernel(const int* __restrict__ offsets,
                                                           const int2* __restrict__ pairs,
                                                           const float* __restrict__ x,
                                                           float* __restrict__ dis,
                                                           __half* __restrict__ g, int n) {
    int node = blockIdx.x * 16 + (threadIdx.x >> 4);
    int q = threadIdx.x & 15;
    if (node >= n) return;
    int j0 = offsets[node], end = offsets[node + 1];
    float s = 0.f;
    for (int j = j0 + q; j < end; j += 16) s += __int_as_float(pairs[j].y);
    #pragma unroll
    for (int off = 8; off; off >>= 1) s += __shfl_xor(s, off);
    float dn = rsqrtf(1.0f + s);
    if (q == 0) dis[node] = dn;
    float4 v = reinterpret_cast<const float4*>(x)[(size_t)node * 16 + q];
    __half2 pk[2];
    pk[0] = __float22half2_rn(make_float2(dn * v.x, dn * v.y));
    pk[1] = __float22half2_rn(make_float2(dn * v.z, dn * v.w));
    reinterpret_cast<float2*>(g + (size_t)node * 64)[q] = *reinterpret_cast<float2*>(pk);
}

// ---------------------------------------------------------------- aggregation core
// 8-lane group per node; lane q owns half8 #q (features 8q..8q+7). fp32 accum.
__device__ __forceinline__ void accum8(float* acc, float4 rv, float w) {
    const __half2* h = reinterpret_cast<const __half2*>(&rv);
    #pragma unroll
    for (int k = 0; k < 4; ++k) {
        float2 f = __half22float2(h[k]);
        acc[2 * k]     = fmaf(w, f.x, acc[2 * k]);
        acc[2 * k + 1] = fmaf(w, f.y, acc[2 * k + 1]);
    }
}

// R17: batched issue — 8 pairs loads, then 8 gathers, then accumulate.
// Halves the per-node serialized latency chain vs the 4-wide interleave.
__device__ __forceinline__ void agg_node(const float4* __restrict__ gt,
                                         const int2* __restrict__ pairs,
                                         int j, int end, int node, int q,
                                         float* __restrict__ acc) {
    for (; j + 8 <= end; j += 8) {
        int2 p[8];
        #pragma unroll
        for (int u = 0; u < 8; ++u) p[u] = pairs[j + u];
        float4 r[8];
        #pragma unroll
        for (int u = 0; u < 8; ++u) r[u] = gt[(size_t)p[u].x * 8 + q];
        #pragma unroll
        for (int u = 0; u < 8; ++u) accum8(acc, r[u], __int_as_float(p[u].y));
    }
    if (j + 4 <= end) {
        int2 p0 = pairs[j], p1 = pairs[j + 1], p2 = pairs[j + 2], p3 = pairs[j + 3];
        float4 r0 = gt[(size_t)p0.x * 8 + q];
        float4 r1 = gt[(size_t)p1.x * 8 + q];
        float4 r2 = gt[(size_t)p2.x * 8 + q];
        float4 r3 = gt[(size_t)p3.x * 8 + q];
        accum8(acc, r0, __int_as_float(p0.y));
        accum8(acc, r1, __int_as_float(p1.y));
        accum8(acc, r2, __int_as_float(p2.y));
        accum8(acc, r3, __int_as_float(p3.y));
        j += 4;
    }
    for (; j < end; ++j) {
        int2 p = pairs[j];
        float4 r = gt[(size_t)p.x * 8 + q];
        accum8(acc, r, __int_as_float(p.y));
    }
    float4 rs = gt[(size_t)node * 8 + q];   // self term, weight 1
    accum8(acc, rs, 1.0f);
}

// ---- phase 1: wave's 8-lane group aggregates one node into rows (x dis)
__device__ __forceinline__ void phase1_agg(const __half* __restrict__ gin,
                                           const float* __restrict__ dis,
                                           const int* __restrict__ offsets,
                                           const int2* __restrict__ pairs,
                                           __half2 (*rows)[33], int n, int tid,
                                           int blockbase_node) {
    int ln = tid >> 3;
    int q  = tid & 7;
    int gnode = blockbase_node + ln;
    if (gnode < n) {
        const float4* gt = reinterpret_cast<const float4*>(gin);
        float acc[8] = {0.f, 0.f, 0.f, 0.f, 0.f, 0.f, 0.f, 0.f};
        agg_node(gt, pairs, offsets[gnode], offsets[gnode + 1], gnode, q, acc);
        float dn = dis[gnode];
        #pragma unroll
        for (int k2 = 0; k2 < 4; ++k2)
            rows[ln][q * 4 + k2] =
                __float22half2_rn(make_float2(dn * acc[2 * k2], dn * acc[2 * k2 + 1]));
    }
}

// -------------------------------- fused layer 1-3: aggregate -> GEMM64+ELU -> fp16
// Wave-autonomous: wave w aggregates nodes 8w..8w+7, wave-fence, then GEMMs them
// (lane = node(lane&7) x slice(lane>>3), 8 outputs per thread). WT stride 33.
__global__ __launch_bounds__(256) void layer_fused_kernel(const __half* __restrict__ gin,
                                                          const float* __restrict__ dis,
                                                          const int* __restrict__ offsets,
                                                          const int2* __restrict__ pairs,
                                                          const float* __restrict__ W,
                                                          const float* __restrict__ b,
                                                          __half* __restrict__ gout, int n) {
    __shared__ __half2 rows[32][33];
    __shared__ __half2 WT[64][33];   // WT[c][k2] = (W[2k2][c], W[2k2+1][c]) fp16
    __shared__ float bias_s[64];
    for (int idx = threadIdx.x; idx < 64 * 32; idx += 256) {
        int k2 = idx >> 6, c = idx & 63;
        WT[c][k2] = __float22half2_rn(make_float2(W[(2 * k2) * 64 + c],
                                                  W[(2 * k2 + 1) * 64 + c]));
    }
    if (threadIdx.x < 64) bias_s[threadIdx.x] = b[threadIdx.x];
    __syncthreads();          // WT/bias ready (only block barrier)

    int tid = threadIdx.x;
    phase1_agg(gin, dis, offsets, pairs, rows, n, tid, blockIdx.x * 32);
    wave_lds_fence();         // this wave's rows visible to this wave

    int lane  = tid & 63, wave = tid >> 6;
    int node2 = wave * 8 + (lane & 7);
    int slice = lane >> 3;                 // 0..7 -> outputs [8*slice, 8*slice+8)
    int gnode2 = blockIdx.x * 32 + node2;
    if (gnode2 < n) {
        __half2 h2[32];
        #pragma unroll
        for (int i = 0; i < 32; ++i) h2[i] = rows[node2][i];
        float dn = dis[gnode2];
        int c0 = slice * 8;
        float r[8];
        #pragma unroll
        for (int cc = 0; cc < 8; ++cc) {
            const __half2* wt = &WT[c0 + cc][0];
            float a0 = 0.f, a1 = 0.f, a2 = 0.f, a3 = 0.f;
            #pragma unroll
            for (int i = 0; i < 8; ++i) {
                a0 = fdot2f(h2[4 * i],     wt[4 * i],     a0);
                a1 = fdot2f(h2[4 * i + 1], wt[4 * i + 1], a1);
                a2 = fdot2f(h2[4 * i + 2], wt[4 * i + 2], a2);
                a3 = fdot2f(h2[4 * i + 3], wt[4 * i + 3], a3);
            }
            float v = (a0 + a1) + (a2 + a3) + bias_s[c0 + cc];
            v = (v > 0.f) ? v : expm1f(v);          // ELU
            r[cc] = dn * v;                          // pre-scale for next layer
        }
        __half2 pk[4];
        pk[0] = __float22half2_rn(make_float2(r[0], r[1]));
        pk[1] = __float22half2_rn(make_float2(r[2], r[3]));
        pk[2] = __float22half2_rn(make_float2(r[4], r[5]));
        pk[3] = __float22half2_rn(make_float2(r[6], r[7]));
        *reinterpret_cast<float4*>(gout + (size_t)gnode2 * 64 + c0) =
            *reinterpret_cast<float4*>(pk);
    }
}

// ------------- fused layer 4: aggregate -> GEMM40 -> log_softmax -> d_out
__global__ __launch_bounds__(256) void layer4_fused_kernel(const __half* __restrict__ gin,
                                                           const float* __restrict__ dis,
                                                           const int* __restrict__ offsets,
                                                           const int2* __restrict__ pairs,
                                                           const float* __restrict__ W,
                                                           const float* __restrict__ b,
                                                           float* __restrict__ out, int n) {
    __shared__ __half2 rows[32][33];
    __shared__ __half2 WT[40][33];
    __shared__ float bias_s[40];
    for (int idx = threadIdx.x; idx < 40 * 32; idx += 256) {
        int c = idx % 40, k2 = idx / 40;
        WT[c][k2] = __float22half2_rn(make_float2(W[(2 * k2) * 40 + c],
                                                  W[(2 * k2 + 1) * 40 + c]));
    }
    if (threadIdx.x < 40) bias_s[threadIdx.x] = b[threadIdx.x];
    __syncthreads();

    int tid = threadIdx.x;
    phase1_agg(gin, dis, offsets, pairs, rows, n, tid, blockIdx.x * 32);
    wave_lds_fence();

    int lane  = tid & 63, wave = tid >> 6;
    int node2 = wave * 8 + (lane & 7);
    int slice = lane >> 3;                 // classes [5*slice, 5*slice+5)
    int gnode2 = blockIdx.x * 32 + node2;

    float r[5];
    float mp = -__builtin_inff();
    if (gnode2 < n) {
        __half2 h2[32];
        #pragma unroll
        for (int i = 0; i < 32; ++i) h2[i] = rows[node2][i];
        int c0 = slice * 5;
        #pragma unroll
        for (int cc = 0; cc < 5; ++cc) {
            const __half2* wt = &WT[c0 + cc][0];
            float a0 = 0.f, a1 = 0.f, a2 = 0.f, a3 = 0.f;
            #pragma unroll
            for (int i = 0; i < 8; ++i) {
                a0 = fdot2f(h2[4 * i],     wt[4 * i],     a0);
                a1 = fdot2f(h2[4 * i + 1], wt[4 * i + 1], a1);
                a2 = fdot2f(h2[4 * i + 2], wt[4 * i + 2], a2);
                a3 = fdot2f(h2[4 * i + 3], wt[4 * i + 3], a3);
            }
            r[cc] = (a0 + a1) + (a2 + a3) + bias_s[c0 + cc];
            mp = fmaxf(mp, r[cc]);
        }
    }
    // row max/sum over the 8 slices (lanes node2, node2+8, ..., node2+56)
    mp = fmaxf(mp, __shfl_xor(mp, 8));
    mp = fmaxf(mp, __shfl_xor(mp, 16));
    mp = fmaxf(mp, __shfl_xor(mp, 32));
    float sp = 0.f;
    if (gnode2 < n) {
        #pragma unroll
        for (int cc = 0; cc < 5; ++cc) sp += expf(r[cc] - mp);
    }
    sp += __shfl_xor(sp, 8);
    sp += __shfl_xor(sp, 16);
    sp += __shfl_xor(sp, 32);
    if (gnode2 < n) {
        float ls = logf(sp) + mp;
        float* outp = out + (size_t)gnode2 * 40 + slice * 5;
        #pragma unroll
        for (int cc = 0; cc < 5; ++cc) outp[cc] = r[cc] - ls;
    }
}

// ---------------------------------------------------------------- launch

static inline size_t align_up(size_t x, size_t a) { return (x + a - 1) & ~(a - 1); }

extern "C" void kernel_launch(void* const* d_in, const int* in_sizes, int n_in,
                              void* d_out, int out_size, void* d_ws, size_t ws_size,
                              hipStream_t stream) {
    const float* x  = (const float*)d_in[0];
    const int*   ei = (const int*)d_in[1];     // [2][E] flat: src then dst
    const float* ea = (const float*)d_in[2];
    const float* W1 = (const float*)d_in[3];
    const float* b1 = (const float*)d_in[4];
    const float* W2 = (const float*)d_in[5];
    const float* b2 = (const float*)d_in[6];
    const float* W3 = (const float*)d_in[7];
    const float* b3 = (const float*)d_in[8];
    const float* W4 = (const float*)d_in[9];
    const float* b4 = (const float*)d_in[10];

    const int N = in_sizes[0] / 64;
    const int E = in_sizes[1] / 2;

    const int* src = ei;
    const int* dst = ei + E;

    const int nbuck   = (N + NPB - 1) >> NPB_SHIFT;      // 196 for N=100K (<=256)
    const int nblk_ac = (E + CHUNK - 1) / CHUNK;         // 293

    // workspace carve-up
    char* p = (char*)d_ws;
    int*    offsets     = (int*)p;  p += align_up(((size_t)N + 1) * 4, 256);
    int*    bucket_cnt  = (int*)p;  p += align_up(((size_t)nbuck + 1) * 4, 256);
    int*    bucket_base = (int*)p;  p += align_up(((size_t)nbuck + 1) * 4, 256);
    int*    blockbase   = (int*)p;  p += align_up((size_t)nblk_ac * nbuck * 4, 256);
    float*  dis         = (float*)p; p += align_up((size_t)N * 4, 256);
    int2*   pairs       = (int2*)p;  p += align_up(((size_t)E + 8) * 8, 256);
    int2*   temp        = (int2*)p;  p += align_up(((size_t)E + 8) * 8, 256);
    __half* gA          = (__half*)p; p += align_up((size_t)N * 64 * 2, 256);
    __half* gB          = (__half*)p; p += align_up((size_t)N * 64 * 2, 256);
    (void)ws_size;

    const int nb_g16 = (N + 15) / 16;
    const int nb_f   = (N + 31) / 32;

    // --- CSR build (two-level counting sort, LDS-privatized) ---
    hipMemsetAsync(bucket_cnt, 0, (size_t)(nbuck + 1) * 4, stream);
    bucket_count_kernel<<<nblk_ac, 256, 0, stream>>>(dst, bucket_cnt, blockbase, nbuck, E);
    bucket_scan_kernel<<<1, 64, 0, stream>>>(bucket_cnt, bucket_base, nbuck, E);
    bucket_scatter_kernel<<<nblk_ac, 256, 0, stream>>>(src, dst, ea, bucket_base,
                                                       blockbase, temp, nbuck, E);
    bucket_csr_kernel<<<nbuck, 256, 0, stream>>>(temp, bucket_base, offsets, pairs, N, E);
    rowsum_scale_kernel<<<nb_g16, 256, 0, stream>>>(offsets, pairs, x, dis, gA, N);

    // --- layers 1..3 fused (aggregate -> GEMM64+ELU -> fp16), wave-autonomous ---
    layer_fused_kernel<<<nb_f, 256, 0, stream>>>(gA, dis, offsets, pairs, W1, b1, gB, N);
    layer_fused_kernel<<<nb_f, 256, 0, stream>>>(gB, dis, offsets, pairs, W2, b2, gA, N);
    layer_fused_kernel<<<nb_f, 256, 0, stream>>>(gA, dis, offsets, pairs, W3, b3, gB, N);

    // --- layer 4 fused: aggregate -> GEMM40 -> log_softmax -> d_out ---
    layer4_fused_kernel<<<nb_f, 256, 0, stream>>>(gB, dis, offsets, pairs, W4, b4,
                                                  (float*)d_out, N);
}

// Round 18
// 210.154 us; speedup vs baseline: 7.2771x; 1.1418x over previous
//
#include <hip/hip_runtime.h>
#include <hip/hip_fp16.h>
#include <cstdint>
#include <cmath>

// GCN, 4 layers. Structure: A(hW) = (Ah)W with norm folded into features:
//   g = dis (.) h  stored FP16,
//   A_norm h [d] = dis[d] * ( sum_e w_e * g[src_e] + g[d] )
// CSR via two-level LDS counting sort (R12). Layers wave-autonomous (R13).
//
// R18: EXACT revert to R13's aggregation loop (4-wide interleave). Completed
// experiment matrix on the agg loop: R14 fp16-pack (null, VALU not binding),
// R15 dual-node (-24%, occupancy loss), R16 edge-parallel LDS atomics (-7x),
// R17 8-deep batch (-15%, VGPR 32->52 halved occupancy). R13's config
// {4-wide, 32 VGPR, 56% occ, 0 conflicts} is the ridge. Per-layer gather is
// pinned at 1.7-2.1 TB/s L2-miss fabric rate across all six variants ->
// that is the floor for random 128-B row gathers from an L3-resident buffer.

#define NPB_SHIFT 9
#define NPB 512              // nodes per bucket
#define CHUNK 4096           // edges per block in count/scatter passes

// ---- fdot2: 2x f16 MAC with fp32 accumulator (guarded builtin)
__device__ __forceinline__ float fdot2f(__half2 a, __half2 b, float c) {
#if defined(__has_builtin)
#if __has_builtin(__builtin_amdgcn_fdot2)
    typedef _Float16 h2v __attribute__((ext_vector_type(2)));
    return __builtin_amdgcn_fdot2(__builtin_bit_cast(h2v, a),
                                  __builtin_bit_cast(h2v, b), c, false);
#else
    float2 fa = __half22float2(a), fb = __half22float2(b);
    return fmaf(fa.x, fb.x, fmaf(fa.y, fb.y, c));
#endif
#else
    float2 fa = __half22float2(a), fb = __half22float2(b);
    return fmaf(fa.x, fb.x, fmaf(fa.y, fb.y, c));
#endif
}

// ---- wave-local LDS fence: all this wave's ds_writes visible to its ds_reads
__device__ __forceinline__ void wave_lds_fence() {
    asm volatile("s_waitcnt lgkmcnt(0)" ::: "memory");
    __builtin_amdgcn_wave_barrier();
    __builtin_amdgcn_sched_barrier(0);
}

// ------------------------------------------- CSR build: two-level counting sort

__global__ __launch_bounds__(256) void bucket_count_kernel(const int* __restrict__ dst,
                                                           int* __restrict__ bucket_cnt,
                                                           int* __restrict__ blockbase,
                                                           int nbuck, int E) {
    __shared__ int hist[256];
    int tid = threadIdx.x;
    hist[tid] = 0;
    __syncthreads();
    int base = blockIdx.x * CHUNK;
    #pragma unroll
    for (int u = 0; u < CHUNK / 256; ++u) {
        int e = base + u * 256 + tid;
        if (e < E) atomicAdd(&hist[dst[e] >> NPB_SHIFT], 1);
    }
    __syncthreads();
    if (tid < nbuck)
        blockbase[blockIdx.x * nbuck + tid] = atomicAdd(&bucket_cnt[tid], hist[tid]);
}

__global__ __launch_bounds__(64) void bucket_scan_kernel(const int* __restrict__ bucket_cnt,
                                                         int* __restrict__ bucket_base,
                                                         int nbuck, int E) {
    int lane = threadIdx.x;
    int run = 0;
    for (int b0 = 0; b0 < nbuck; b0 += 64) {
        int i = b0 + lane;
        int v = (i < nbuck) ? bucket_cnt[i] : 0;
        int x = v;
        #pragma unroll
        for (int off = 1; off < 64; off <<= 1) {
            int t = __shfl_up(x, off);
            if (lane >= off) x += t;
        }
        if (i < nbuck) bucket_base[i] = run + x - v;
        run += __shfl(x, 63);
    }
    if (lane == 0) bucket_base[nbuck] = E;
}

__global__ __launch_bounds__(256) void bucket_scatter_kernel(const int* __restrict__ src,
                                                             const int* __restrict__ dst,
                                                             const float* __restrict__ w,
                                                             const int* __restrict__ bucket_base,
                                                             const int* __restrict__ blockbase,
                                                             int2* __restrict__ temp,
                                                             int nbuck, int E) {
    __shared__ int cursor[256];
    int tid = threadIdx.x;
    if (tid < nbuck)
        cursor[tid] = bucket_base[tid] + blockbase[blockIdx.x * nbuck + tid];
    __syncthreads();
    int base = blockIdx.x * CHUNK;
    #pragma unroll
    for (int u = 0; u < CHUNK / 256; ++u) {
        int e = base + u * 256 + tid;
        if (e < E) {
            int d = dst[e];
            int pos = atomicAdd(&cursor[d >> NPB_SHIFT], 1);
            temp[pos] = make_int2(src[e] | ((d & (NPB - 1)) << 17),
                                  __float_as_int(w[e]));
        }
    }
}

__global__ __launch_bounds__(256) void bucket_csr_kernel(const int2* __restrict__ temp,
                                                         const int* __restrict__ bucket_base,
                                                         int* __restrict__ offsets,
                                                         int2* __restrict__ pairs,
                                                         int n, int E) {
    __shared__ int cnt[NPB];
    __shared__ int wtot[4];
    int tid = threadIdx.x;
    int bk = blockIdx.x;
    int base = bucket_base[bk], end = bucket_base[bk + 1];
    cnt[tid] = 0; cnt[tid + 256] = 0;
    __syncthreads();
    for (int j = base + tid; j < end; j += 256)
        atomicAdd(&cnt[temp[j].x >> 17], 1);
    __syncthreads();
    int a0 = cnt[2 * tid], a1 = cnt[2 * tid + 1];
    int s = a0 + a1;
    int lane = tid & 63, wid = tid >> 6;
    int x = s;
    #pragma unroll
    for (int off = 1; off < 64; off <<= 1) {
        int t2 = __shfl_up(x, off);
        if (lane >= off) x += t2;
    }
    if (lane == 63) wtot[wid] = x;
    __syncthreads();
    int wbase = 0;
    #pragma unroll
    for (int wv = 0; wv < 4; ++wv) if (wv < wid) wbase += wtot[wv];
    int e0 = wbase + x - s;
    int abs0 = base + e0, abs1 = base + e0 + a0;
    int node0 = bk * NPB + 2 * tid;
    if (node0 < n)     offsets[node0]     = abs0;
    if (node0 + 1 < n) offsets[node0 + 1] = abs1;
    __syncthreads();
    cnt[2 * tid] = abs0; cnt[2 * tid + 1] = abs1;
    __syncthreads();
    for (int j = base + tid; j < end; j += 256) {
        int2 t2 = temp[j];
        int pos = atomicAdd(&cnt[t2.x >> 17], 1);
        pairs[pos] = make_int2(t2.x & 0x1FFFF, t2.y);
    }
    if (bk == 0 && tid == 0) offsets[n] = E;
}

// fused: deg row-sum -> dis -> g0 = fp16(dis (.) x). 16 lanes per node.
__global__ __launch_bounds__(256) void rowsum_scale_kernel(const int* __restrict__ offsets,
                                                           const int2* __restrict__ pairs,
                                                           const float* __restrict__ x,
                                                           float* __restrict__ dis,
                                                           __half* __restrict__ g, int n) {
    int node = blockIdx.x * 16 + (threadIdx.x >> 4);
    int q = threadIdx.x & 15;
    if (node >= n) return;
    int j0 = offsets[node], end = offsets[node + 1];
    float s = 0.f;
    for (int j = j0 + q; j < end; j += 16) s += __int_as_float(pairs[j].y);
    #pragma unroll
    for (int off = 8; off; off >>= 1) s += __shfl_xor(s, off);
    float dn = rsqrtf(1.0f + s);
    if (q == 0) dis[node] = dn;
    float4 v = reinterpret_cast<const float4*>(x)[(size_t)node * 16 + q];
    __half2 pk[2];
    pk[0] = __float22half2_rn(make_float2(dn * v.x, dn * v.y));
    pk[1] = __float22half2_rn(make_float2(dn * v.z, dn * v.w));
    reinterpret_cast<float2*>(g + (size_t)node * 64)[q] = *reinterpret_cast<float2*>(pk);
}

// ---------------------------------------------------------------- aggregation core
// 8-lane group per node; lane q owns half8 #q (features 8q..8q+7). fp32 accum.
// R13-proven 4-wide interleave — do not change (R14/R15/R16/R17 all regressed).
__device__ __forceinline__ void accum8(float* acc, float4 rv, float w) {
    const __half2* h = reinterpret_cast<const __half2*>(&rv);
    #pragma unroll
    for (int k = 0; k < 4; ++k) {
        float2 f = __half22float2(h[k]);
        acc[2 * k]     = fmaf(w, f.x, acc[2 * k]);
        acc[2 * k + 1] = fmaf(w, f.y, acc[2 * k + 1]);
    }
}

__device__ __forceinline__ void agg_node(const float4* __restrict__ gt,
                                         const int2* __restrict__ pairs,
                                         int j, int end, int node, int q,
                                         float* __restrict__ acc) {
    for (; j + 4 <= end; j += 4) {
        int2 p0 = pairs[j], p1 = pairs[j + 1], p2 = pairs[j + 2], p3 = pairs[j + 3];
        float4 r0 = gt[(size_t)p0.x * 8 + q];
        float4 r1 = gt[(size_t)p1.x * 8 + q];
        float4 r2 = gt[(size_t)p2.x * 8 + q];
        float4 r3 = gt[(size_t)p3.x * 8 + q];
        accum8(acc, r0, __int_as_float(p0.y));
        accum8(acc, r1, __int_as_float(p1.y));
        accum8(acc, r2, __int_as_float(p2.y));
        accum8(acc, r3, __int_as_float(p3.y));
    }
    for (; j < end; ++j) {
        int2 p = pairs[j];
        float4 r = gt[(size_t)p.x * 8 + q];
        accum8(acc, r, __int_as_float(p.y));
    }
    float4 rs = gt[(size_t)node * 8 + q];   // self term, weight 1
    accum8(acc, rs, 1.0f);
}

// ---- phase 1: wave's 8-lane group aggregates one node into rows (x dis)
__device__ __forceinline__ void phase1_agg(const __half* __restrict__ gin,
                                           const float* __restrict__ dis,
                                           const int* __restrict__ offsets,
                                           const int2* __restrict__ pairs,
                                           __half2 (*rows)[33], int n, int tid,
                                           int blockbase_node) {
    int ln = tid >> 3;
    int q  = tid & 7;
    int gnode = blockbase_node + ln;
    if (gnode < n) {
        const float4* gt = reinterpret_cast<const float4*>(gin);
        float acc[8] = {0.f, 0.f, 0.f, 0.f, 0.f, 0.f, 0.f, 0.f};
        agg_node(gt, pairs, offsets[gnode], offsets[gnode + 1], gnode, q, acc);
        float dn = dis[gnode];
        #pragma unroll
        for (int k2 = 0; k2 < 4; ++k2)
            rows[ln][q * 4 + k2] =
                __float22half2_rn(make_float2(dn * acc[2 * k2], dn * acc[2 * k2 + 1]));
    }
}

// -------------------------------- fused layer 1-3: aggregate -> GEMM64+ELU -> fp16
// Wave-autonomous: wave w aggregates nodes 8w..8w+7, wave-fence, then GEMMs them
// (lane = node(lane&7) x slice(lane>>3), 8 outputs per thread). WT stride 33.
__global__ __launch_bounds__(256) void layer_fused_kernel(const __half* __restrict__ gin,
                                                          const float* __restrict__ dis,
                                                          const int* __restrict__ offsets,
                                                          const int2* __restrict__ pairs,
                                                          const float* __restrict__ W,
                                                          const float* __restrict__ b,
                                                          __half* __restrict__ gout, int n) {
    __shared__ __half2 rows[32][33];
    __shared__ __half2 WT[64][33];   // WT[c][k2] = (W[2k2][c], W[2k2+1][c]) fp16
    __shared__ float bias_s[64];
    for (int idx = threadIdx.x; idx < 64 * 32; idx += 256) {
        int k2 = idx >> 6, c = idx & 63;
        WT[c][k2] = __float22half2_rn(make_float2(W[(2 * k2) * 64 + c],
                                                  W[(2 * k2 + 1) * 64 + c]));
    }
    if (threadIdx.x < 64) bias_s[threadIdx.x] = b[threadIdx.x];
    __syncthreads();          // WT/bias ready (only block barrier)

    int tid = threadIdx.x;
    phase1_agg(gin, dis, offsets, pairs, rows, n, tid, blockIdx.x * 32);
    wave_lds_fence();         // this wave's rows visible to this wave

    int lane  = tid & 63, wave = tid >> 6;
    int node2 = wave * 8 + (lane & 7);
    int slice = lane >> 3;                 // 0..7 -> outputs [8*slice, 8*slice+8)
    int gnode2 = blockIdx.x * 32 + node2;
    if (gnode2 < n) {
        __half2 h2[32];
        #pragma unroll
        for (int i = 0; i < 32; ++i) h2[i] = rows[node2][i];
        float dn = dis[gnode2];
        int c0 = slice * 8;
        float r[8];
        #pragma unroll
        for (int cc = 0; cc < 8; ++cc) {
            const __half2* wt = &WT[c0 + cc][0];
            float a0 = 0.f, a1 = 0.f, a2 = 0.f, a3 = 0.f;
            #pragma unroll
            for (int i = 0; i < 8; ++i) {
                a0 = fdot2f(h2[4 * i],     wt[4 * i],     a0);
                a1 = fdot2f(h2[4 * i + 1], wt[4 * i + 1], a1);
                a2 = fdot2f(h2[4 * i + 2], wt[4 * i + 2], a2);
                a3 = fdot2f(h2[4 * i + 3], wt[4 * i + 3], a3);
            }
            float v = (a0 + a1) + (a2 + a3) + bias_s[c0 + cc];
            v = (v > 0.f) ? v : expm1f(v);          // ELU
            r[cc] = dn * v;                          // pre-scale for next layer
        }
        __half2 pk[4];
        pk[0] = __float22half2_rn(make_float2(r[0], r[1]));
        pk[1] = __float22half2_rn(make_float2(r[2], r[3]));
        pk[2] = __float22half2_rn(make_float2(r[4], r[5]));
        pk[3] = __float22half2_rn(make_float2(r[6], r[7]));
        *reinterpret_cast<float4*>(gout + (size_t)gnode2 * 64 + c0) =
            *reinterpret_cast<float4*>(pk);
    }
}

// ------------- fused layer 4: aggregate -> GEMM40 -> log_softmax -> d_out
__global__ __launch_bounds__(256) void layer4_fused_kernel(const __half* __restrict__ gin,
                                                           const float* __restrict__ dis,
                                                           const int* __restrict__ offsets,
                                                           const int2* __restrict__ pairs,
                                                           const float* __restrict__ W,
                                                           const float* __restrict__ b,
                                                           float* __restrict__ out, int n) {
    __shared__ __half2 rows[32][33];
    __shared__ __half2 WT[40][33];
    __shared__ float bias_s[40];
    for (int idx = threadIdx.x; idx < 40 * 32; idx += 256) {
        int c = idx % 40, k2 = idx / 40;
        WT[c][k2] = __float22half2_rn(make_float2(W[(2 * k2) * 40 + c],
                                                  W[(2 * k2 + 1) * 40 + c]));
    }
    if (threadIdx.x < 40) bias_s[threadIdx.x] = b[threadIdx.x];
    __syncthreads();

    int tid = threadIdx.x;
    phase1_agg(gin, dis, offsets, pairs, rows, n, tid, blockIdx.x * 32);
    wave_lds_fence();

    int lane  = tid & 63, wave = tid >> 6;
    int node2 = wave * 8 + (lane & 7);
    int slice = lane >> 3;                 // classes [5*slice, 5*slice+5)
    int gnode2 = blockIdx.x * 32 + node2;

    float r[5];
    float mp = -__builtin_inff();
    if (gnode2 < n) {
        __half2 h2[32];
        #pragma unroll
        for (int i = 0; i < 32; ++i) h2[i] = rows[node2][i];
        int c0 = slice * 5;
        #pragma unroll
        for (int cc = 0; cc < 5; ++cc) {
            const __half2* wt = &WT[c0 + cc][0];
            float a0 = 0.f, a1 = 0.f, a2 = 0.f, a3 = 0.f;
            #pragma unroll
            for (int i = 0; i < 8; ++i) {
                a0 = fdot2f(h2[4 * i],     wt[4 * i],     a0);
                a1 = fdot2f(h2[4 * i + 1], wt[4 * i + 1], a1);
                a2 = fdot2f(h2[4 * i + 2], wt[4 * i + 2], a2);
                a3 = fdot2f(h2[4 * i + 3], wt[4 * i + 3], a3);
            }
            r[cc] = (a0 + a1) + (a2 + a3) + bias_s[c0 + cc];
            mp = fmaxf(mp, r[cc]);
        }
    }
    // row max/sum over the 8 slices (lanes node2, node2+8, ..., node2+56)
    mp = fmaxf(mp, __shfl_xor(mp, 8));
    mp = fmaxf(mp, __shfl_xor(mp, 16));
    mp = fmaxf(mp, __shfl_xor(mp, 32));
    float sp = 0.f;
    if (gnode2 < n) {
        #pragma unroll
        for (int cc = 0; cc < 5; ++cc) sp += expf(r[cc] - mp);
    }
    sp += __shfl_xor(sp, 8);
    sp += __shfl_xor(sp, 16);
    sp += __shfl_xor(sp, 32);
    if (gnode2 < n) {
        float ls = logf(sp) + mp;
        float* outp = out + (size_t)gnode2 * 40 + slice * 5;
        #pragma unroll
        for (int cc = 0; cc < 5; ++cc) outp[cc] = r[cc] - ls;
    }
}

// ---------------------------------------------------------------- launch

static inline size_t align_up(size_t x, size_t a) { return (x + a - 1) & ~(a - 1); }

extern "C" void kernel_launch(void* const* d_in, const int* in_sizes, int n_in,
                              void* d_out, int out_size, void* d_ws, size_t ws_size,
                              hipStream_t stream) {
    const float* x  = (const float*)d_in[0];
    const int*   ei = (const int*)d_in[1];     // [2][E] flat: src then dst
    const float* ea = (const float*)d_in[2];
    const float* W1 = (const float*)d_in[3];
    const float* b1 = (const float*)d_in[4];
    const float* W2 = (const float*)d_in[5];
    const float* b2 = (const float*)d_in[6];
    const float* W3 = (const float*)d_in[7];
    const float* b3 = (const float*)d_in[8];
    const float* W4 = (const float*)d_in[9];
    const float* b4 = (const float*)d_in[10];

    const int N = in_sizes[0] / 64;
    const int E = in_sizes[1] / 2;

    const int* src = ei;
    const int* dst = ei + E;

    const int nbuck   = (N + NPB - 1) >> NPB_SHIFT;      // 196 for N=100K (<=256)
    const int nblk_ac = (E + CHUNK - 1) / CHUNK;         // 293

    // workspace carve-up
    char* p = (char*)d_ws;
    int*    offsets     = (int*)p;  p += align_up(((size_t)N + 1) * 4, 256);
    int*    bucket_cnt  = (int*)p;  p += align_up(((size_t)nbuck + 1) * 4, 256);
    int*    bucket_base = (int*)p;  p += align_up(((size_t)nbuck + 1) * 4, 256);
    int*    blockbase   = (int*)p;  p += align_up((size_t)nblk_ac * nbuck * 4, 256);
    float*  dis         = (float*)p; p += align_up((size_t)N * 4, 256);
    int2*   pairs       = (int2*)p;  p += align_up(((size_t)E + 8) * 8, 256);
    int2*   temp        = (int2*)p;  p += align_up(((size_t)E + 8) * 8, 256);
    __half* gA          = (__half*)p; p += align_up((size_t)N * 64 * 2, 256);
    __half* gB          = (__half*)p; p += align_up((size_t)N * 64 * 2, 256);
    (void)ws_size;

    const int nb_g16 = (N + 15) / 16;
    const int nb_f   = (N + 31) / 32;

    // --- CSR build (two-level counting sort, LDS-privatized) ---
    hipMemsetAsync(bucket_cnt, 0, (size_t)(nbuck + 1) * 4, stream);
    bucket_count_kernel<<<nblk_ac, 256, 0, stream>>>(dst, bucket_cnt, blockbase, nbuck, E);
    bucket_scan_kernel<<<1, 64, 0, stream>>>(bucket_cnt, bucket_base, nbuck, E);
    bucket_scatter_kernel<<<nblk_ac, 256, 0, stream>>>(src, dst, ea, bucket_base,
                                                       blockbase, temp, nbuck, E);
    bucket_csr_kernel<<<nbuck, 256, 0, stream>>>(temp, bucket_base, offsets, pairs, N, E);
    rowsum_scale_kernel<<<nb_g16, 256, 0, stream>>>(offsets, pairs, x, dis, gA, N);

    // --- layers 1..3 fused (aggregate -> GEMM64+ELU -> fp16), wave-autonomous ---
    layer_fused_kernel<<<nb_f, 256, 0, stream>>>(gA, dis, offsets, pairs, W1, b1, gB, N);
    layer_fused_kernel<<<nb_f, 256, 0, stream>>>(gB, dis, offsets, pairs, W2, b2, gA, N);
    layer_fused_kernel<<<nb_f, 256, 0, stream>>>(gA, dis, offsets, pairs, W3, b3, gB, N);

    // --- layer 4 fused: aggregate -> GEMM40 -> log_softmax -> d_out ---
    layer4_fused_kernel<<<nb_f, 256, 0, stream>>>(gB, dis, offsets, pairs, W4, b4,
                                                  (float*)d_out, N);
}

// Round 19
// 196.035 us; speedup vs baseline: 7.8012x; 1.0720x over previous
//
#include <hip/hip_runtime.h>
#include <hip/hip_fp16.h>
#include <cstdint>
#include <cmath>

// GCN, 4 layers. Structure: A(hW) = (Ah)W with norm folded into features:
//   g = dis (.) h  -- R19: stored FP8 e4m3 x16 (rows 64B, halves the pinned
//   gather traffic; R6->R7 proved the gather is bytes-bound).
//   A_norm h [d] = dis[d] * ( sum_e w_e * g[src_e] + g[d] )
// CSR via two-level LDS counting sort (R12). Layers wave-autonomous (R13).
// Agg loop: R13's 4-wide interleave (six-variant matrix closed, all others
// regressed). Quantization once per layer output: LDS handoff + GEMMs stay
// fp16/fp32; decode/encode via native v_cvt_pk_*_fp8 (guarded builtins).
// 16x storage scale avoids subnormals; 1/16 folds into phase1's dn multiply.

#define NPB_SHIFT 9
#define NPB 512              // nodes per bucket
#define CHUNK 4096           // edges per block in count/scatter passes

// ---------------------------------------------------------------- fp8 helpers
#if defined(__has_builtin)
#if __has_builtin(__builtin_amdgcn_cvt_pk_f32_fp8) && __has_builtin(__builtin_amdgcn_cvt_pk_fp8_f32)
#define HAVE_FP8_CVT 1
#endif
#endif

typedef float f32x2_t __attribute__((ext_vector_type(2)));

__device__ __forceinline__ void fp8x4_to_f32(unsigned u, float* f) {
#ifdef HAVE_FP8_CVT
    f32x2_t lo = __builtin_amdgcn_cvt_pk_f32_fp8((int)u, false);
    f32x2_t hi = __builtin_amdgcn_cvt_pk_f32_fp8((int)u, true);
    f[0] = lo[0]; f[1] = lo[1]; f[2] = hi[0]; f[3] = hi[1];
#else
    #pragma unroll
    for (int i = 0; i < 4; ++i) {
        unsigned b = (u >> (8 * i)) & 0xFFu;
        unsigned s = b >> 7, e = (b >> 3) & 0xFu, m = b & 7u;
        float v = e ? ldexpf((float)(8 + m), (int)e - 10) : ldexpf((float)m, -9);
        f[i] = s ? -v : v;
    }
#endif
}

__device__ __forceinline__ unsigned f32_to_fp8_sw(float f) {
    unsigned s = (f < 0.f) ? 0x80u : 0u;
    f = fabsf(f);
    if (f >= 448.f) return s | 0x7Eu;
    if (f < ldexpf(1.f, -10)) return s;
    int e; float m = frexpf(f, &e);              // f = m*2^e, m in [0.5,1)
    int E = e - 1 + 7;
    int M = (int)(m * 16.f + 0.5f) - 8;
    if (M == 8) { M = 0; ++E; }
    if (E <= 0) {
        int Ms = (int)(f * 512.f + 0.5f);
        return (Ms > 7) ? (s | 0x08u) : (s | (unsigned)Ms);
    }
    if (E >= 16) return s | 0x7Eu;
    return s | ((unsigned)E << 3) | (unsigned)M;
}

__device__ __forceinline__ unsigned fp8_pack_lo(float a, float b, unsigned old) {
    a = fminf(fmaxf(a, -448.f), 448.f);
    b = fminf(fmaxf(b, -448.f), 448.f);
#ifdef HAVE_FP8_CVT
    return (unsigned)__builtin_amdgcn_cvt_pk_fp8_f32(a, b, (int)old, false);
#else
    return (old & 0xFFFF0000u) | f32_to_fp8_sw(a) | (f32_to_fp8_sw(b) << 8);
#endif
}

__device__ __forceinline__ unsigned fp8_pack_hi(float a, float b, unsigned old) {
    a = fminf(fmaxf(a, -448.f), 448.f);
    b = fminf(fmaxf(b, -448.f), 448.f);
#ifdef HAVE_FP8_CVT
    return (unsigned)__builtin_amdgcn_cvt_pk_fp8_f32(a, b, (int)old, true);
#else
    return (old & 0x0000FFFFu) | (f32_to_fp8_sw(a) << 16) | (f32_to_fp8_sw(b) << 24);
#endif
}

// ---- fdot2: 2x f16 MAC with fp32 accumulator (guarded builtin)
__device__ __forceinline__ float fdot2f(__half2 a, __half2 b, float c) {
#if defined(__has_builtin)
#if __has_builtin(__builtin_amdgcn_fdot2)
    typedef _Float16 h2v __attribute__((ext_vector_type(2)));
    return __builtin_amdgcn_fdot2(__builtin_bit_cast(h2v, a),
                                  __builtin_bit_cast(h2v, b), c, false);
#else
    float2 fa = __half22float2(a), fb = __half22float2(b);
    return fmaf(fa.x, fb.x, fmaf(fa.y, fb.y, c));
#endif
#else
    float2 fa = __half22float2(a), fb = __half22float2(b);
    return fmaf(fa.x, fb.x, fmaf(fa.y, fb.y, c));
#endif
}

// ---- wave-local LDS fence: all this wave's ds_writes visible to its ds_reads
__device__ __forceinline__ void wave_lds_fence() {
    asm volatile("s_waitcnt lgkmcnt(0)" ::: "memory");
    __builtin_amdgcn_wave_barrier();
    __builtin_amdgcn_sched_barrier(0);
}

// ------------------------------------------- CSR build: two-level counting sort

__global__ __launch_bounds__(256) void bucket_count_kernel(const int* __restrict__ dst,
                                                           int* __restrict__ bucket_cnt,
                                                           int* __restrict__ blockbase,
                                                           int nbuck, int E) {
    __shared__ int hist[256];
    int tid = threadIdx.x;
    hist[tid] = 0;
    __syncthreads();
    int base = blockIdx.x * CHUNK;
    #pragma unroll
    for (int u = 0; u < CHUNK / 256; ++u) {
        int e = base + u * 256 + tid;
        if (e < E) atomicAdd(&hist[dst[e] >> NPB_SHIFT], 1);
    }
    __syncthreads();
    if (tid < nbuck)
        blockbase[blockIdx.x * nbuck + tid] = atomicAdd(&bucket_cnt[tid], hist[tid]);
}

__global__ __launch_bounds__(64) void bucket_scan_kernel(const int* __restrict__ bucket_cnt,
                                                         int* __restrict__ bucket_base,
                                                         int nbuck, int E) {
    int lane = threadIdx.x;
    int run = 0;
    for (int b0 = 0; b0 < nbuck; b0 += 64) {
        int i = b0 + lane;
        int v = (i < nbuck) ? bucket_cnt[i] : 0;
        int x = v;
        #pragma unroll
        for (int off = 1; off < 64; off <<= 1) {
            int t = __shfl_up(x, off);
            if (lane >= off) x += t;
        }
        if (i < nbuck) bucket_base[i] = run + x - v;
        run += __shfl(x, 63);
    }
    if (lane == 0) bucket_base[nbuck] = E;
}

__global__ __launch_bounds__(256) void bucket_scatter_kernel(const int* __restrict__ src,
                                                             const int* __restrict__ dst,
                                                             const float* __restrict__ w,
                                                             const int* __restrict__ bucket_base,
                                                             const int* __restrict__ blockbase,
                                                             int2* __restrict__ temp,
                                                             int nbuck, int E) {
    __shared__ int cursor[256];
    int tid = threadIdx.x;
    if (tid < nbuck)
        cursor[tid] = bucket_base[tid] + blockbase[blockIdx.x * nbuck + tid];
    __syncthreads();
    int base = blockIdx.x * CHUNK;
    #pragma unroll
    for (int u = 0; u < CHUNK / 256; ++u) {
        int e = base + u * 256 + tid;
        if (e < E) {
            int d = dst[e];
            int pos = atomicAdd(&cursor[d >> NPB_SHIFT], 1);
            temp[pos] = make_int2(src[e] | ((d & (NPB - 1)) << 17),
                                  __float_as_int(w[e]));
        }
    }
}

__global__ __launch_bounds__(256) void bucket_csr_kernel(const int2* __restrict__ temp,
                                                         const int* __restrict__ bucket_base,
                                                         int* __restrict__ offsets,
                                                         int2* __restrict__ pairs,
                                                         int n, int E) {
    __shared__ int cnt[NPB];
    __shared__ int wtot[4];
    int tid = threadIdx.x;
    int bk = blockIdx.x;
    int base = bucket_base[bk], end = bucket_base[bk + 1];
    cnt[tid] = 0; cnt[tid + 256] = 0;
    __syncthreads();
    for (int j = base + tid; j < end; j += 256)
        atomicAdd(&cnt[temp[j].x >> 17], 1);
    __syncthreads();
    int a0 = cnt[2 * tid], a1 = cnt[2 * tid + 1];
    int s = a0 + a1;
    int lane = tid & 63, wid = tid >> 6;
    int x = s;
    #pragma unroll
    for (int off = 1; off < 64; off <<= 1) {
        int t2 = __shfl_up(x, off);
        if (lane >= off) x += t2;
    }
    if (lane == 63) wtot[wid] = x;
    __syncthreads();
    int wbase = 0;
    #pragma unroll
    for (int wv = 0; wv < 4; ++wv) if (wv < wid) wbase += wtot[wv];
    int e0 = wbase + x - s;
    int abs0 = base + e0, abs1 = base + e0 + a0;
    int node0 = bk * NPB + 2 * tid;
    if (node0 < n)     offsets[node0]     = abs0;
    if (node0 + 1 < n) offsets[node0 + 1] = abs1;
    __syncthreads();
    cnt[2 * tid] = abs0; cnt[2 * tid + 1] = abs1;
    __syncthreads();
    for (int j = base + tid; j < end; j += 256) {
        int2 t2 = temp[j];
        int pos = atomicAdd(&cnt[t2.x >> 17], 1);
        pairs[pos] = make_int2(t2.x & 0x1FFFF, t2.y);
    }
    if (bk == 0 && tid == 0) offsets[n] = E;
}

// fused: deg row-sum -> dis -> g0 = fp8(16 * dis (.) x). 16 lanes per node.
__global__ __launch_bounds__(256) void rowsum_scale_kernel(const int* __restrict__ offsets,
                                                           const int2* __restrict__ pairs,
                                                           const float* __restrict__ x,
                                                           float* __restrict__ dis,
                                                           unsigned char* __restrict__ g, int n) {
    int node = blockIdx.x * 16 + (threadIdx.x >> 4);
    int q = threadIdx.x & 15;
    if (node >= n) return;
    int j0 = offsets[node], end = offsets[node + 1];
    float s = 0.f;
    for (int j = j0 + q; j < end; j += 16) s += __int_as_float(pairs[j].y);
    #pragma unroll
    for (int off = 8; off; off >>= 1) s += __shfl_xor(s, off);
    float dn = rsqrtf(1.0f + s);
    if (q == 0) dis[node] = dn;
    float dnE = dn * 16.0f;                           // storage scale
    float4 v = reinterpret_cast<const float4*>(x)[(size_t)node * 16 + q];
    unsigned u = fp8_pack_lo(dnE * v.x, dnE * v.y, 0u);
    u = fp8_pack_hi(dnE * v.z, dnE * v.w, u);
    reinterpret_cast<unsigned*>(g)[(size_t)node * 16 + q] = u;   // 4 fp8 per lane
}

// ---------------------------------------------------------------- aggregation core
// 8-lane group per node; lane q owns fp8x8 slot #q (features 8q..8q+7, 8 bytes).
// fp32 accum. R13-proven 4-wide interleave — do not change.
__device__ __forceinline__ void accum8(float* acc, uint2 rv, float w) {
    float f[8];
    fp8x4_to_f32(rv.x, f);
    fp8x4_to_f32(rv.y, f + 4);
    #pragma unroll
    for (int k = 0; k < 8; ++k) acc[k] = fmaf(w, f[k], acc[k]);
}

__device__ __forceinline__ void agg_node(const uint2* __restrict__ gt,
                                         const int2* __restrict__ pairs,
                                         int j, int end, int node, int q,
                                         float* __restrict__ acc) {
    for (; j + 4 <= end; j += 4) {
        int2 p0 = pairs[j], p1 = pairs[j + 1], p2 = pairs[j + 2], p3 = pairs[j + 3];
        uint2 r0 = gt[(size_t)p0.x * 8 + q];
        uint2 r1 = gt[(size_t)p1.x * 8 + q];
        uint2 r2 = gt[(size_t)p2.x * 8 + q];
        uint2 r3 = gt[(size_t)p3.x * 8 + q];
        accum8(acc, r0, __int_as_float(p0.y));
        accum8(acc, r1, __int_as_float(p1.y));
        accum8(acc, r2, __int_as_float(p2.y));
        accum8(acc, r3, __int_as_float(p3.y));
    }
    for (; j < end; ++j) {
        int2 p = pairs[j];
        uint2 r = gt[(size_t)p.x * 8 + q];
        accum8(acc, r, __int_as_float(p.y));
    }
    uint2 rs = gt[(size_t)node * 8 + q];   // self term, weight 1
    accum8(acc, rs, 1.0f);
}

// ---- phase 1: wave's 8-lane group aggregates one node into rows (x dis/16)
__device__ __forceinline__ void phase1_agg(const unsigned char* __restrict__ gin,
                                           const float* __restrict__ dis,
                                           const int* __restrict__ offsets,
                                           const int2* __restrict__ pairs,
                                           __half2 (*rows)[33], int n, int tid,
                                           int blockbase_node) {
    int ln = tid >> 3;
    int q  = tid & 7;
    int gnode = blockbase_node + ln;
    if (gnode < n) {
        const uint2* gt = reinterpret_cast<const uint2*>(gin);
        float acc[8] = {0.f, 0.f, 0.f, 0.f, 0.f, 0.f, 0.f, 0.f};
        agg_node(gt, pairs, offsets[gnode], offsets[gnode + 1], gnode, q, acc);
        float dn = dis[gnode] * 0.0625f;              // undo 16x storage scale
        #pragma unroll
        for (int k2 = 0; k2 < 4; ++k2)
            rows[ln][q * 4 + k2] =
                __float22half2_rn(make_float2(dn * acc[2 * k2], dn * acc[2 * k2 + 1]));
    }
}

// -------------------------------- fused layer 1-3: aggregate -> GEMM64+ELU -> fp8
// Wave-autonomous: wave w aggregates nodes 8w..8w+7, wave-fence, then GEMMs them
// (lane = node(lane&7) x slice(lane>>3), 8 outputs per thread). WT stride 33.
__global__ __launch_bounds__(256) void layer_fused_kernel(const unsigned char* __restrict__ gin,
                                                          const float* __restrict__ dis,
                                                          const int* __restrict__ offsets,
                                                          const int2* __restrict__ pairs,
                                                          const float* __restrict__ W,
                                                          const float* __restrict__ b,
                                                          unsigned char* __restrict__ gout, int n) {
    __shared__ __half2 rows[32][33];
    __shared__ __half2 WT[64][33];   // WT[c][k2] = (W[2k2][c], W[2k2+1][c]) fp16
    __shared__ float bias_s[64];
    for (int idx = threadIdx.x; idx < 64 * 32; idx += 256) {
        int k2 = idx >> 6, c = idx & 63;
        WT[c][k2] = __float22half2_rn(make_float2(W[(2 * k2) * 64 + c],
                                                  W[(2 * k2 + 1) * 64 + c]));
    }
    if (threadIdx.x < 64) bias_s[threadIdx.x] = b[threadIdx.x];
    __syncthreads();          // WT/bias ready (only block barrier)

    int tid = threadIdx.x;
    phase1_agg(gin, dis, offsets, pairs, rows, n, tid, blockIdx.x * 32);
    wave_lds_fence();         // this wave's rows visible to this wave

    int lane  = tid & 63, wave = tid >> 6;
    int node2 = wave * 8 + (lane & 7);
    int slice = lane >> 3;                 // 0..7 -> outputs [8*slice, 8*slice+8)
    int gnode2 = blockIdx.x * 32 + node2;
    if (gnode2 < n) {
        __half2 h2[32];
        #pragma unroll
        for (int i = 0; i < 32; ++i) h2[i] = rows[node2][i];
        float dn16 = dis[gnode2] * 16.0f;  // pre-scale for next layer, x16 storage
        int c0 = slice * 8;
        float r[8];
        #pragma unroll
        for (int cc = 0; cc < 8; ++cc) {
            const __half2* wt = &WT[c0 + cc][0];
            float a0 = 0.f, a1 = 0.f, a2 = 0.f, a3 = 0.f;
            #pragma unroll
            for (int i = 0; i < 8; ++i) {
                a0 = fdot2f(h2[4 * i],     wt[4 * i],     a0);
                a1 = fdot2f(h2[4 * i + 1], wt[4 * i + 1], a1);
                a2 = fdot2f(h2[4 * i + 2], wt[4 * i + 2], a2);
                a3 = fdot2f(h2[4 * i + 3], wt[4 * i + 3], a3);
            }
            float v = (a0 + a1) + (a2 + a3) + bias_s[c0 + cc];
            v = (v > 0.f) ? v : expm1f(v);          // ELU
            r[cc] = dn16 * v;
        }
        unsigned u0 = fp8_pack_lo(r[0], r[1], 0u);
        u0 = fp8_pack_hi(r[2], r[3], u0);
        unsigned u1 = fp8_pack_lo(r[4], r[5], 0u);
        u1 = fp8_pack_hi(r[6], r[7], u1);
        *reinterpret_cast<uint2*>(gout + (size_t)gnode2 * 64 + c0) = make_uint2(u0, u1);
    }
}

// ------------- fused layer 4: aggregate -> GEMM40 -> log_softmax -> d_out
__global__ __launch_bounds__(256) void layer4_fused_kernel(const unsigned char* __restrict__ gin,
                                                           const float* __restrict__ dis,
                                                           const int* __restrict__ offsets,
                                                           const int2* __restrict__ pairs,
                                                           const float* __restrict__ W,
                                                           const float* __restrict__ b,
                                                           float* __restrict__ out, int n) {
    __shared__ __half2 rows[32][33];
    __shared__ __half2 WT[40][33];
    __shared__ float bias_s[40];
    for (int idx = threadIdx.x; idx < 40 * 32; idx += 256) {
        int c = idx % 40, k2 = idx / 40;
        WT[c][k2] = __float22half2_rn(make_float2(W[(2 * k2) * 40 + c],
                                                  W[(2 * k2 + 1) * 40 + c]));
    }
    if (threadIdx.x < 40) bias_s[threadIdx.x] = b[threadIdx.x];
    __syncthreads();

    int tid = threadIdx.x;
    phase1_agg(gin, dis, offsets, pairs, rows, n, tid, blockIdx.x * 32);
    wave_lds_fence();

    int lane  = tid & 63, wave = tid >> 6;
    int node2 = wave * 8 + (lane & 7);
    int slice = lane >> 3;                 // classes [5*slice, 5*slice+5)
    int gnode2 = blockIdx.x * 32 + node2;

    float r[5];
    float mp = -__builtin_inff();
    if (gnode2 < n) {
        __half2 h2[32];
        #pragma unroll
        for (int i = 0; i < 32; ++i) h2[i] = rows[node2][i];
        int c0 = slice * 5;
        #pragma unroll
        for (int cc = 0; cc < 5; ++cc) {
            const __half2* wt = &WT[c0 + cc][0];
            float a0 = 0.f, a1 = 0.f, a2 = 0.f, a3 = 0.f;
            #pragma unroll
            for (int i = 0; i < 8; ++i) {
                a0 = fdot2f(h2[4 * i],     wt[4 * i],     a0);
                a1 = fdot2f(h2[4 * i + 1], wt[4 * i + 1], a1);
                a2 = fdot2f(h2[4 * i + 2], wt[4 * i + 2], a2);
                a3 = fdot2f(h2[4 * i + 3], wt[4 * i + 3], a3);
            }
            r[cc] = (a0 + a1) + (a2 + a3) + bias_s[c0 + cc];
            mp = fmaxf(mp, r[cc]);
        }
    }
    // row max/sum over the 8 slices (lanes node2, node2+8, ..., node2+56)
    mp = fmaxf(mp, __shfl_xor(mp, 8));
    mp = fmaxf(mp, __shfl_xor(mp, 16));
    mp = fmaxf(mp, __shfl_xor(mp, 32));
    float sp = 0.f;
    if (gnode2 < n) {
        #pragma unroll
        for (int cc = 0; cc < 5; ++cc) sp += expf(r[cc] - mp);
    }
    sp += __shfl_xor(sp, 8);
    sp += __shfl_xor(sp, 16);
    sp += __shfl_xor(sp, 32);
    if (gnode2 < n) {
        float ls = logf(sp) + mp;
        float* outp = out + (size_t)gnode2 * 40 + slice * 5;
        #pragma unroll
        for (int cc = 0; cc < 5; ++cc) outp[cc] = r[cc] - ls;
    }
}

// ---------------------------------------------------------------- launch

static inline size_t align_up(size_t x, size_t a) { return (x + a - 1) & ~(a - 1); }

extern "C" void kernel_launch(void* const* d_in, const int* in_sizes, int n_in,
                              void* d_out, int out_size, void* d_ws, size_t ws_size,
                              hipStream_t stream) {
    const float* x  = (const float*)d_in[0];
    const int*   ei = (const int*)d_in[1];     // [2][E] flat: src then dst
    const float* ea = (const float*)d_in[2];
    const float* W1 = (const float*)d_in[3];
    const float* b1 = (const float*)d_in[4];
    const float* W2 = (const float*)d_in[5];
    const float* b2 = (const float*)d_in[6];
    const float* W3 = (const float*)d_in[7];
    const float* b3 = (const float*)d_in[8];
    const float* W4 = (const float*)d_in[9];
    const float* b4 = (const float*)d_in[10];

    const int N = in_sizes[0] / 64;
    const int E = in_sizes[1] / 2;

    const int* src = ei;
    const int* dst = ei + E;

    const int nbuck   = (N + NPB - 1) >> NPB_SHIFT;      // 196 for N=100K (<=256)
    const int nblk_ac = (E + CHUNK - 1) / CHUNK;         // 293

    // workspace carve-up
    char* p = (char*)d_ws;
    int*    offsets     = (int*)p;  p += align_up(((size_t)N + 1) * 4, 256);
    int*    bucket_cnt  = (int*)p;  p += align_up(((size_t)nbuck + 1) * 4, 256);
    int*    bucket_base = (int*)p;  p += align_up(((size_t)nbuck + 1) * 4, 256);
    int*    blockbase   = (int*)p;  p += align_up((size_t)nblk_ac * nbuck * 4, 256);
    float*  dis         = (float*)p; p += align_up((size_t)N * 4, 256);
    int2*   pairs       = (int2*)p;  p += align_up(((size_t)E + 8) * 8, 256);
    int2*   temp        = (int2*)p;  p += align_up(((size_t)E + 8) * 8, 256);
    unsigned char* gA   = (unsigned char*)p; p += align_up((size_t)N * 64, 256);
    unsigned char* gB   = (unsigned char*)p; p += align_up((size_t)N * 64, 256);
    (void)ws_size;

    const int nb_g16 = (N + 15) / 16;
    const int nb_f   = (N + 31) / 32;

    // --- CSR build (two-level counting sort, LDS-privatized) ---
    hipMemsetAsync(bucket_cnt, 0, (size_t)(nbuck + 1) * 4, stream);
    bucket_count_kernel<<<nblk_ac, 256, 0, stream>>>(dst, bucket_cnt, blockbase, nbuck, E);
    bucket_scan_kernel<<<1, 64, 0, stream>>>(bucket_cnt, bucket_base, nbuck, E);
    bucket_scatter_kernel<<<nblk_ac, 256, 0, stream>>>(src, dst, ea, bucket_base,
                                                       blockbase, temp, nbuck, E);
    bucket_csr_kernel<<<nbuck, 256, 0, stream>>>(temp, bucket_base, offsets, pairs, N, E);
    rowsum_scale_kernel<<<nb_g16, 256, 0, stream>>>(offsets, pairs, x, dis, gA, N);

    // --- layers 1..3 fused (aggregate -> GEMM64+ELU -> fp8), wave-autonomous ---
    layer_fused_kernel<<<nb_f, 256, 0, stream>>>(gA, dis, offsets, pairs, W1, b1, gB, N);
    layer_fused_kernel<<<nb_f, 256, 0, stream>>>(gB, dis, offsets, pairs, W2, b2, gA, N);
    layer_fused_kernel<<<nb_f, 256, 0, stream>>>(gA, dis, offsets, pairs, W3, b3, gB, N);

    // --- layer 4 fused: aggregate -> GEMM40 -> log_softmax -> d_out ---
    layer4_fused_kernel<<<nb_f, 256, 0, stream>>>(gB, dis, offsets, pairs, W4, b4,
                                                  (float*)d_out, N);
}